// Round 6
// baseline (2271.386 us; speedup 1.0000x reference)
//
#include <hip/hip_runtime.h>

#define B_ 4
#define S_ 2048
#define H_ 1024
#define L_ 4
#define N_ 4
#define D_ 256
#define V_ 256
#define EPSF 1e-5f
#define WH_ ((size_t)H_ * H_)   // 1<<20

typedef __attribute__((ext_vector_type(8))) short short8;
typedef __attribute__((ext_vector_type(4))) float f32x4;

__device__ inline float bf2f(unsigned short u) {
    union { unsigned int ui; float f; } c; c.ui = ((unsigned int)u) << 16; return c.f;
}
__device__ inline unsigned short f2bf(float f) {
    union { float f; unsigned int ui; } c; c.f = f;
    unsigned int u = c.ui;
    unsigned int r = (u + 0x7FFFu + ((u >> 16) & 1u)) >> 16;
    return (unsigned short)r;
}
__device__ inline float wave64_sum(float v) {
    for (int m = 32; m >= 1; m >>= 1) v += __shfl_xor(v, m, 64);
    return v;
}
__device__ inline void gl_lds16(const unsigned short* g, unsigned short* l) {
    __builtin_amdgcn_global_load_lds(
        (const __attribute__((address_space(1))) unsigned int*)g,
        (__attribute__((address_space(3))) unsigned int*)l, 16, 0, 0);
}

// ---------------------------------------------------------------------------
// fp32 -> bf16 weight convert (contiguous)
// ---------------------------------------------------------------------------
__global__ void wcvt_kernel(const float* __restrict__ W,
                            unsigned short* __restrict__ Wb, int n8) {
    int idx = blockIdx.x * 256 + threadIdx.x;
    if (idx >= n8) return;
    size_t base = (size_t)idx * 8;
    float4 a0 = *(const float4*)(W + base);
    float4 a1 = *(const float4*)(W + base + 4);
    short8 t;
    t[0] = f2bf(a0.x); t[1] = f2bf(a0.y); t[2] = f2bf(a0.z); t[3] = f2bf(a0.w);
    t[4] = f2bf(a1.x); t[5] = f2bf(a1.y); t[6] = f2bf(a1.z); t[7] = f2bf(a1.w);
    *(short8*)(Wb + base) = t;
}

// fp32 -> bf16 into QKV-fused layout: src (L,WH) -> dst layer*3WH + sel*WH
__global__ void wcvt_qkv(const float* __restrict__ W,
                         unsigned short* __restrict__ Wb, int n8, int sel) {
    int idx = blockIdx.x * 256 + threadIdx.x;
    if (idx >= n8) return;
    size_t p = (size_t)idx * 8;
    size_t layer = p >> 20;
    size_t within = p & (WH_ - 1);
    size_t dst = layer * 3 * WH_ + (size_t)sel * WH_ + within;
    float4 a0 = *(const float4*)(W + p);
    float4 a1 = *(const float4*)(W + p + 4);
    short8 t;
    t[0] = f2bf(a0.x); t[1] = f2bf(a0.y); t[2] = f2bf(a0.z); t[3] = f2bf(a0.w);
    t[4] = f2bf(a1.x); t[5] = f2bf(a1.y); t[6] = f2bf(a1.z); t[7] = f2bf(a1.w);
    *(short8*)(Wb + dst) = t;
}

// combined weight: Wo = bf16(Wa + Wb2 + I) per HxH layer (layers contiguous)
__global__ void wadd_kernel(const float* __restrict__ Wa, const float* __restrict__ Wb2,
                            unsigned short* __restrict__ Wo, int n8) {
    int idx = blockIdx.x * 256 + threadIdx.x;
    if (idx >= n8) return;
    size_t base = (size_t)idx * 8;
    short8 t;
#pragma unroll
    for (int e = 0; e < 8; e++) {
        size_t p = base + e;
        int pos = (int)(p & (WH_ - 1));
        float v = Wa[p] + Wb2[p] + (((pos >> 10) == (pos & (H_ - 1))) ? 1.f : 0.f);
        t[e] = f2bf(v);
    }
    *(short8*)(Wo + base) = t;
}

// ---------------------------------------------------------------------------
__global__ void gather_kernel(const int* __restrict__ ids,
                              const float* __restrict__ embed,
                              unsigned short* __restrict__ x) {
    size_t idx = (size_t)blockIdx.x * 256 + threadIdx.x;
    int bs = (int)(idx >> 10);
    int h  = (int)(idx & 1023);
    x[idx] = f2bf(embed[(size_t)ids[bs] * H_ + h]);
}

__global__ void mean_kernel(const unsigned short* __restrict__ Xin,
                            float* __restrict__ xmean) {
    int idx = blockIdx.x * 256 + threadIdx.x;
    int b = idx >> 10, h = idx & 1023;
    int s0 = blockIdx.y * 128;
    const unsigned short* p = Xin + ((size_t)b * S_ + s0) * H_ + h;
    float s = 0.f;
    for (int i = 0; i < 128; i++) s += bf2f(p[(size_t)i * H_]);
    atomicAdd(&xmean[idx], s);
}

__global__ void nm_kernel(const float* __restrict__ xmean,
                          const float* __restrict__ w,
                          const float* __restrict__ bias,
                          float* __restrict__ dopnor) {
    int wave = threadIdx.x >> 6, lane = threadIdx.x & 63;
    for (int p = wave; p < 2 * B_; p += 4) {
        int b = p >> 1, j = p & 1;
        float s = 0.f;
        for (int h = lane; h < H_; h += 64) s += xmean[b * H_ + h] * w[j * H_ + h];
        s = wave64_sum(s);
        if (lane == 0) dopnor[p] = s / (float)S_ + bias[j];
    }
}

__global__ void gain_kernel(const float* __restrict__ xmean,
                            const float* __restrict__ gw,
                            const float* __restrict__ gb,
                            float* __restrict__ qscale) {
    int wave = threadIdx.x >> 6, lane = threadIdx.x & 63;
    for (int p = wave; p < B_ * N_; p += 4) {
        int b = p >> 2, n = p & 3;
        float s = 0.f;
        for (int h = lane; h < H_; h += 64) s += xmean[b * H_ + h] * gw[n * H_ + h];
        s = wave64_sum(s);
        if (lane == 0) qscale[p] = (1.f + s / (float)S_ + gb[n]) * 0.0625f;
    }
}

// ---------------------------------------------------------------------------
// GEMM (m97 structure): C(MxN) = epilogue( A(MxK) @ W(NxK)^T + bias )
// modes: 0 plain->bf16; 1 gate; 2 noise; 3 residual; 4 silu; 5 plain->fp32;
//        6 V^T store
// ---------------------------------------------------------------------------
__global__ __launch_bounds__(256) void gemm_bt(
    const unsigned short* __restrict__ A, const unsigned short* __restrict__ W,
    const float* __restrict__ bias, void* __restrict__ Cout,
    const unsigned short* __restrict__ X, const float* __restrict__ scal,
    int K, int Nout, int mode) {
    __shared__ unsigned short As[128 * 32];
    __shared__ unsigned short Bs[128 * 32];
    int tid = threadIdx.x;
    int wave = tid >> 6, lane = tid & 63;
    int quad = lane >> 4, l16 = lane & 15;
    int bm = blockIdx.x * 128;
    int bn = blockIdx.y * 128;
    int mw = (wave >> 1) * 64, nw = (wave & 1) * 64;

    const unsigned short* Ag = A + (size_t)(bm + wave * 16 + (lane >> 2)) * K + (lane & 3) * 8;
    const unsigned short* Wg = W + (size_t)(bn + wave * 16 + (lane >> 2)) * K + (lane & 3) * 8;
    unsigned short* ldsA = As + wave * 512;
    unsigned short* ldsB = Bs + wave * 512;
    size_t rowskip = (size_t)64 * K;

    f32x4 acc[4][4];
#pragma unroll
    for (int i = 0; i < 4; i++)
#pragma unroll
        for (int j = 0; j < 4; j++)
#pragma unroll
            for (int r = 0; r < 4; r++) acc[i][j][r] = 0.f;

    for (int kk = 0; kk < K; kk += 32) {
        __syncthreads();
        gl_lds16(Ag + kk, ldsA);
        gl_lds16(Ag + rowskip + kk, ldsA + 2048);
        gl_lds16(Wg + kk, ldsB);
        gl_lds16(Wg + rowskip + kk, ldsB + 2048);
        __syncthreads();

        short8 af[4], bfr[4];
#pragma unroll
        for (int i = 0; i < 4; i++)
            af[i] = *(const short8*)&As[(mw + i * 16 + l16) * 32 + quad * 8];
#pragma unroll
        for (int j = 0; j < 4; j++)
            bfr[j] = *(const short8*)&Bs[(nw + j * 16 + l16) * 32 + quad * 8];
#pragma unroll
        for (int i = 0; i < 4; i++)
#pragma unroll
            for (int j = 0; j < 4; j++)
                acc[i][j] = __builtin_amdgcn_mfma_f32_16x16x32_bf16(af[i], bfr[j], acc[i][j], 0, 0, 0);
    }

    if (mode == 6) {
#pragma unroll
        for (int i = 0; i < 4; i++) {
#pragma unroll
            for (int j = 0; j < 4; j++) {
                int col = bn + nw + j * 16 + l16;
                float bv = bias ? bias[col] : 0.f;
                int n = col >> 8, d = col & 255;
                int row0 = bm + mw + i * 16 + quad * 4;
                int b = row0 >> 11, s0 = row0 & 2047;
                union { unsigned short u[4]; uint2 v; } pk;
#pragma unroll
                for (int r = 0; r < 4; r++) pk.u[r] = f2bf(acc[i][j][r] + bv);
                *(uint2*)((unsigned short*)Cout +
                          ((size_t)(b * N_ + n) * D_ + d) * S_ + s0) = pk.v;
            }
        }
        return;
    }

#pragma unroll
    for (int i = 0; i < 4; i++) {
#pragma unroll
        for (int j = 0; j < 4; j++) {
            int col = bn + nw + j * 16 + l16;
            float bv = bias ? bias[col] : 0.f;
#pragma unroll
            for (int r = 0; r < 4; r++) {
                int row = bm + mw + i * 16 + quad * 4 + r;
                float v = acc[i][j][r] + bv;
                size_t off = (size_t)row * Nout + col;
                if (mode == 5) {
                    ((float*)Cout)[off] = v;
                    continue;
                }
                float outv;
                if (mode == 0) {
                    outv = v;
                } else if (mode == 1) {
                    float sig = 1.f / (1.f + __expf(-v));
                    float dop = scal[(row >> 11) * 2];
                    outv = bf2f(X[off]) * (1.f + dop * sig);
                } else if (mode == 2) {
                    float nor = scal[(row >> 11) * 2 + 1];
                    outv = bf2f(X[off]) + nor * tanhf(v);
                } else if (mode == 3) {
                    outv = v + bf2f(X[off]);
                } else {
                    outv = v * (1.f / (1.f + __expf(-v)));
                }
                ((unsigned short*)Cout)[off] = f2bf(outv);
            }
        }
    }
}

// ---------------------------------------------------------------------------
// Fused QKV GEMM: W is (3H x H) fused [q;k;v] for one layer. N=3072.
// col block (64-aligned) selects destination: 0 -> Q, 1 -> K, 2 -> V^T store.
// ---------------------------------------------------------------------------
__global__ __launch_bounds__(256) void gemm_qkv(
    const unsigned short* __restrict__ A, const unsigned short* __restrict__ W,
    const float* __restrict__ qb, const float* __restrict__ kb,
    const float* __restrict__ vbb, unsigned short* __restrict__ Qo,
    unsigned short* __restrict__ Ko, unsigned short* __restrict__ Vt) {
    __shared__ unsigned short As[128 * 32];
    __shared__ unsigned short Bs[128 * 32];
    const int K = H_;
    int tid = threadIdx.x;
    int wave = tid >> 6, lane = tid & 63;
    int quad = lane >> 4, l16 = lane & 15;
    int bm = blockIdx.x * 128;
    int bn = blockIdx.y * 128;
    int mw = (wave >> 1) * 64, nw = (wave & 1) * 64;

    const unsigned short* Ag = A + (size_t)(bm + wave * 16 + (lane >> 2)) * K + (lane & 3) * 8;
    const unsigned short* Wg = W + (size_t)(bn + wave * 16 + (lane >> 2)) * K + (lane & 3) * 8;
    unsigned short* ldsA = As + wave * 512;
    unsigned short* ldsB = Bs + wave * 512;
    size_t rowskip = (size_t)64 * K;

    f32x4 acc[4][4];
#pragma unroll
    for (int i = 0; i < 4; i++)
#pragma unroll
        for (int j = 0; j < 4; j++)
#pragma unroll
            for (int r = 0; r < 4; r++) acc[i][j][r] = 0.f;

    for (int kk = 0; kk < K; kk += 32) {
        __syncthreads();
        gl_lds16(Ag + kk, ldsA);
        gl_lds16(Ag + rowskip + kk, ldsA + 2048);
        gl_lds16(Wg + kk, ldsB);
        gl_lds16(Wg + rowskip + kk, ldsB + 2048);
        __syncthreads();

        short8 af[4], bfr[4];
#pragma unroll
        for (int i = 0; i < 4; i++)
            af[i] = *(const short8*)&As[(mw + i * 16 + l16) * 32 + quad * 8];
#pragma unroll
        for (int j = 0; j < 4; j++)
            bfr[j] = *(const short8*)&Bs[(nw + j * 16 + l16) * 32 + quad * 8];
#pragma unroll
        for (int i = 0; i < 4; i++)
#pragma unroll
            for (int j = 0; j < 4; j++)
                acc[i][j] = __builtin_amdgcn_mfma_f32_16x16x32_bf16(af[i], bfr[j], acc[i][j], 0, 0, 0);
    }

    int sel = (bn + nw) >> 10;   // uniform per block-half
    if (sel == 2) {
#pragma unroll
        for (int i = 0; i < 4; i++) {
#pragma unroll
            for (int j = 0; j < 4; j++) {
                int c2 = ((bn + nw) & 1023) + j * 16 + l16;
                float bv = vbb[c2];
                int n = c2 >> 8, d = c2 & 255;
                int row0 = bm + mw + i * 16 + quad * 4;
                int b = row0 >> 11, s0 = row0 & 2047;
                union { unsigned short u[4]; uint2 v; } pk;
#pragma unroll
                for (int r = 0; r < 4; r++) pk.u[r] = f2bf(acc[i][j][r] + bv);
                *(uint2*)(Vt + ((size_t)(b * N_ + n) * D_ + d) * S_ + s0) = pk.v;
            }
        }
    } else {
        unsigned short* Co = (sel == 0) ? Qo : Ko;
        const float* bias = (sel == 0) ? qb : kb;
#pragma unroll
        for (int i = 0; i < 4; i++) {
#pragma unroll
            for (int j = 0; j < 4; j++) {
                int c2 = ((bn + nw) & 1023) + j * 16 + l16;
                float bv = bias[c2];
#pragma unroll
                for (int r = 0; r < 4; r++) {
                    int row = bm + mw + i * 16 + quad * 4 + r;
                    Co[(size_t)row * H_ + c2] = f2bf(acc[i][j][r] + bv);
                }
            }
        }
    }
}

// ---------------------------------------------------------------------------
// Flash attention (fallback, round-5): 8 waves x 16 q, full t-range.
// ---------------------------------------------------------------------------
__global__ __launch_bounds__(512) void flash_attn(
    const unsigned short* __restrict__ Q, const unsigned short* __restrict__ Kg,
    const unsigned short* __restrict__ VT, const float* __restrict__ qscale,
    unsigned short* __restrict__ O) {
    __shared__ unsigned short Kt[64][264];
    __shared__ unsigned short Vtl[272][72];
    __shared__ unsigned short Pl[8][16][72];

    int tid = threadIdx.x;
    int wave = tid >> 6, lane = tid & 63;
    int quad = lane >> 4, l16 = lane & 15;
    int bnh = blockIdx.y;
    size_t base = ((size_t)(bnh >> 2) * S_) * H_ + (size_t)(bnh & 3) * D_;
    size_t vtbase = (size_t)bnh * D_ * S_;
    int qw = blockIdx.x * 128 + wave * 16;
    float scale = qscale[bnh];

    for (int c = tid; c < 16 * 72; c += 512) {
        int rr = c / 72, cc = c - rr * 72;
        Vtl[256 + rr][cc] = (rr == 0) ? (unsigned short)0x3F80 : (unsigned short)0;
    }

    short8 qf[8];
#pragma unroll
    for (int kk = 0; kk < 8; kk++)
        qf[kk] = *(const short8*)(Q + base + (size_t)(qw + l16) * H_ + kk * 32 + quad * 8);

    f32x4 o[16], osum;
#pragma unroll
    for (int c = 0; c < 16; c++)
#pragma unroll
        for (int r = 0; r < 4; r++) o[c][r] = 0.f;
#pragma unroll
    for (int r = 0; r < 4; r++) osum[r] = 0.f;
    float mrow[4] = {-1e30f, -1e30f, -1e30f, -1e30f};

    for (int t0 = 0; t0 < S_; t0 += 64) {
        __syncthreads();
#pragma unroll
        for (int rr = 0; rr < 4; rr++) {
            int c = rr * 512 + tid;
            int row = c >> 5, col = (c & 31) * 8;
            *(short8*)&Kt[row][col] =
                *(const short8*)(Kg + base + (size_t)(t0 + row) * H_ + col);
        }
#pragma unroll
        for (int rr = 0; rr < 4; rr++) {
            int c = rr * 512 + tid;
            int d = c >> 3, col = (c & 7) * 8;
            *(short8*)&Vtl[d][col] =
                *(const short8*)(VT + vtbase + (size_t)d * S_ + t0 + col);
        }
        __syncthreads();

        f32x4 s[4];
#pragma unroll
        for (int j = 0; j < 4; j++)
#pragma unroll
            for (int r = 0; r < 4; r++) s[j][r] = 0.f;
#pragma unroll
        for (int j = 0; j < 4; j++)
#pragma unroll
            for (int kk = 0; kk < 8; kk++) {
                short8 kf = *(const short8*)&Kt[j * 16 + l16][kk * 32 + quad * 8];
                s[j] = __builtin_amdgcn_mfma_f32_16x16x32_bf16(qf[kk], kf, s[j], 0, 0, 0);
            }

        float alpha[4];
#pragma unroll
        for (int r = 0; r < 4; r++) {
            float sv[4];
#pragma unroll
            for (int j = 0; j < 4; j++) sv[j] = s[j][r] * scale;
            float mx = fmaxf(fmaxf(sv[0], sv[1]), fmaxf(sv[2], sv[3]));
            for (int m = 8; m >= 1; m >>= 1) mx = fmaxf(mx, __shfl_xor(mx, m, 64));
            float mnew = fmaxf(mrow[r], mx);
            alpha[r] = __expf(mrow[r] - mnew);
            mrow[r] = mnew;
#pragma unroll
            for (int j = 0; j < 4; j++)
                Pl[wave][quad * 4 + r][j * 16 + l16] = f2bf(__expf(sv[j] - mnew));
        }
#pragma unroll
        for (int c = 0; c < 16; c++)
#pragma unroll
            for (int r = 0; r < 4; r++) o[c][r] *= alpha[r];
#pragma unroll
        for (int r = 0; r < 4; r++) osum[r] *= alpha[r];

        short8 pf0 = *(const short8*)&Pl[wave][l16][quad * 8];
        short8 pf1 = *(const short8*)&Pl[wave][l16][32 + quad * 8];
#pragma unroll
        for (int c = 0; c < 16; c++) {
            short8 vf0 = *(const short8*)&Vtl[c * 16 + l16][quad * 8];
            o[c] = __builtin_amdgcn_mfma_f32_16x16x32_bf16(pf0, vf0, o[c], 0, 0, 0);
            short8 vf1 = *(const short8*)&Vtl[c * 16 + l16][32 + quad * 8];
            o[c] = __builtin_amdgcn_mfma_f32_16x16x32_bf16(pf1, vf1, o[c], 0, 0, 0);
        }
        {
            short8 vs0 = *(const short8*)&Vtl[256 + l16][quad * 8];
            osum = __builtin_amdgcn_mfma_f32_16x16x32_bf16(pf0, vs0, osum, 0, 0, 0);
            short8 vs1 = *(const short8*)&Vtl[256 + l16][32 + quad * 8];
            osum = __builtin_amdgcn_mfma_f32_16x16x32_bf16(pf1, vs1, osum, 0, 0, 0);
        }
    }

    float invl[4];
#pragma unroll
    for (int r = 0; r < 4; r++)
        invl[r] = 1.f / __shfl(osum[r], (lane & 48), 64);
#pragma unroll
    for (int c = 0; c < 16; c++)
#pragma unroll
        for (int r = 0; r < 4; r++) {
            int row = qw + quad * 4 + r;
            int d = c * 16 + l16;
            O[base + (size_t)row * H_ + d] = f2bf(o[c][r] * invl[r]);
        }
}

// ---------------------------------------------------------------------------
// Flash split: grid (8 qblk, 2 t-half, 16 bnh), 512 thr, 32 q-rows/wave.
// Each block: 256 q-rows x 1024 t. Writes normalized partial O (bf16) +
// per-row (m,l) fp32. kf/vf LDS reads amortized over 2 row-tiles.
// ---------------------------------------------------------------------------
__global__ __launch_bounds__(512) void flash_split(
    const unsigned short* __restrict__ Q, const unsigned short* __restrict__ Kg,
    const unsigned short* __restrict__ VT, const float* __restrict__ qscale,
    unsigned short* __restrict__ Pout, float2* __restrict__ ml) {
    __shared__ unsigned short Kt[64][264];
    __shared__ unsigned short Vtl[272][72];
    __shared__ unsigned short Pl[8][32][72];

    int tid = threadIdx.x;
    int wave = tid >> 6, lane = tid & 63;
    int quad = lane >> 4, l16 = lane & 15;
    int bnh = blockIdx.z;
    int half = blockIdx.y;
    size_t base = ((size_t)(bnh >> 2) * S_) * H_ + (size_t)(bnh & 3) * D_;
    size_t vtbase = (size_t)bnh * D_ * S_;
    int qw = blockIdx.x * 256 + wave * 32;
    float scale = qscale[bnh];
    unsigned short* Ph = Pout + (size_t)half * B_ * S_ * H_;

    for (int c = tid; c < 16 * 72; c += 512) {
        int rr = c / 72, cc = c - rr * 72;
        Vtl[256 + rr][cc] = (rr == 0) ? (unsigned short)0x3F80 : (unsigned short)0;
    }

    short8 qf[2][8];
#pragma unroll
    for (int rt = 0; rt < 2; rt++)
#pragma unroll
        for (int kk = 0; kk < 8; kk++)
            qf[rt][kk] = *(const short8*)(Q + base +
                (size_t)(qw + rt * 16 + l16) * H_ + kk * 32 + quad * 8);

    f32x4 o[2][16], osum[2];
#pragma unroll
    for (int rt = 0; rt < 2; rt++) {
#pragma unroll
        for (int c = 0; c < 16; c++)
#pragma unroll
            for (int r = 0; r < 4; r++) o[rt][c][r] = 0.f;
#pragma unroll
        for (int r = 0; r < 4; r++) osum[rt][r] = 0.f;
    }
    float mrow[2][4];
#pragma unroll
    for (int rt = 0; rt < 2; rt++)
#pragma unroll
        for (int r = 0; r < 4; r++) mrow[rt][r] = -1e30f;

    int tbeg = half * (S_ / 2);
    for (int tt = 0; tt < S_ / 2; tt += 64) {
        int t0 = tbeg + tt;
        __syncthreads();
#pragma unroll
        for (int rr = 0; rr < 4; rr++) {
            int c = rr * 512 + tid;
            int row = c >> 5, col = (c & 31) * 8;
            *(short8*)&Kt[row][col] =
                *(const short8*)(Kg + base + (size_t)(t0 + row) * H_ + col);
        }
#pragma unroll
        for (int rr = 0; rr < 4; rr++) {
            int c = rr * 512 + tid;
            int d = c >> 3, col = (c & 7) * 8;
            *(short8*)&Vtl[d][col] =
                *(const short8*)(VT + vtbase + (size_t)d * S_ + t0 + col);
        }
        __syncthreads();

        // QK^T for both row-tiles, kf read once
        f32x4 s0[4], s1[4];
#pragma unroll
        for (int j = 0; j < 4; j++)
#pragma unroll
            for (int r = 0; r < 4; r++) { s0[j][r] = 0.f; s1[j][r] = 0.f; }
#pragma unroll
        for (int j = 0; j < 4; j++)
#pragma unroll
            for (int kk = 0; kk < 8; kk++) {
                short8 kf = *(const short8*)&Kt[j * 16 + l16][kk * 32 + quad * 8];
                s0[j] = __builtin_amdgcn_mfma_f32_16x16x32_bf16(qf[0][kk], kf, s0[j], 0, 0, 0);
                s1[j] = __builtin_amdgcn_mfma_f32_16x16x32_bf16(qf[1][kk], kf, s1[j], 0, 0, 0);
            }

        // online softmax per row-tile
#pragma unroll
        for (int rt = 0; rt < 2; rt++) {
            float alpha[4];
#pragma unroll
            for (int r = 0; r < 4; r++) {
                float sv[4];
#pragma unroll
                for (int j = 0; j < 4; j++)
                    sv[j] = (rt == 0 ? s0[j][r] : s1[j][r]) * scale;
                float mx = fmaxf(fmaxf(sv[0], sv[1]), fmaxf(sv[2], sv[3]));
                for (int m = 8; m >= 1; m >>= 1) mx = fmaxf(mx, __shfl_xor(mx, m, 64));
                float mnew = fmaxf(mrow[rt][r], mx);
                alpha[r] = __expf(mrow[rt][r] - mnew);
                mrow[rt][r] = mnew;
#pragma unroll
                for (int j = 0; j < 4; j++)
                    Pl[wave][rt * 16 + quad * 4 + r][j * 16 + l16] =
                        f2bf(__expf(sv[j] - mnew));
            }
#pragma unroll
            for (int c = 0; c < 16; c++)
#pragma unroll
                for (int r = 0; r < 4; r++) o[rt][c][r] *= alpha[r];
#pragma unroll
            for (int r = 0; r < 4; r++) osum[rt][r] *= alpha[r];
        }

        // PV for both row-tiles, vf read once
        short8 pf[2][2];
#pragma unroll
        for (int rt = 0; rt < 2; rt++) {
            pf[rt][0] = *(const short8*)&Pl[wave][rt * 16 + l16][quad * 8];
            pf[rt][1] = *(const short8*)&Pl[wave][rt * 16 + l16][32 + quad * 8];
        }
#pragma unroll
        for (int c = 0; c < 16; c++) {
            short8 vf0 = *(const short8*)&Vtl[c * 16 + l16][quad * 8];
            o[0][c] = __builtin_amdgcn_mfma_f32_16x16x32_bf16(pf[0][0], vf0, o[0][c], 0, 0, 0);
            o[1][c] = __builtin_amdgcn_mfma_f32_16x16x32_bf16(pf[1][0], vf0, o[1][c], 0, 0, 0);
            short8 vf1 = *(const short8*)&Vtl[c * 16 + l16][32 + quad * 8];
            o[0][c] = __builtin_amdgcn_mfma_f32_16x16x32_bf16(pf[0][1], vf1, o[0][c], 0, 0, 0);
            o[1][c] = __builtin_amdgcn_mfma_f32_16x16x32_bf16(pf[1][1], vf1, o[1][c], 0, 0, 0);
        }
        {
            short8 vs0 = *(const short8*)&Vtl[256 + l16][quad * 8];
            short8 vs1 = *(const short8*)&Vtl[256 + l16][32 + quad * 8];
            osum[0] = __builtin_amdgcn_mfma_f32_16x16x32_bf16(pf[0][0], vs0, osum[0], 0, 0, 0);
            osum[0] = __builtin_amdgcn_mfma_f32_16x16x32_bf16(pf[0][1], vs1, osum[0], 0, 0, 0);
            osum[1] = __builtin_amdgcn_mfma_f32_16x16x32_bf16(pf[1][0], vs0, osum[1], 0, 0, 0);
            osum[1] = __builtin_amdgcn_mfma_f32_16x16x32_bf16(pf[1][1], vs1, osum[1], 0, 0, 0);
        }
    }

    // write partial: Ô = o / l (bf16), plus (m, l) at l16==0 lanes
#pragma unroll
    for (int rt = 0; rt < 2; rt++) {
        float invl[4];
#pragma unroll
        for (int r = 0; r < 4; r++)
            invl[r] = 1.f / __shfl(osum[rt][r], (lane & 48), 64);
        if (l16 == 0) {
#pragma unroll
            for (int r = 0; r < 4; r++) {
                int row = qw + rt * 16 + quad * 4 + r;
                float2 v; v.x = mrow[rt][r]; v.y = osum[rt][r];
                ml[((size_t)half * 16 + bnh) * S_ + row] = v;
            }
        }
#pragma unroll
        for (int c = 0; c < 16; c++)
#pragma unroll
            for (int r = 0; r < 4; r++) {
                int row = qw + rt * 16 + quad * 4 + r;
                int d = c * 16 + l16;
                Ph[base + (size_t)row * H_ + d] = f2bf(o[rt][c][r] * invl[r]);
            }
    }
}

// merge two halves: out = (w1*ô1 + w2*ô2)/(w1+w2), wi = li e^{mi-m*}
__global__ __launch_bounds__(256) void flash_merge(
    const unsigned short* __restrict__ P1, const unsigned short* __restrict__ P2,
    const float2* __restrict__ ml, unsigned short* __restrict__ O) {
    size_t e = ((size_t)blockIdx.x * 256 + threadIdx.x) * 8;
    int grow = (int)(e >> 10);
    int h0 = (int)(e & 1023);
    int b = grow >> 11, s = grow & 2047;
    int bnh = b * N_ + (h0 >> 8);
    float2 a = ml[(size_t)bnh * S_ + s];
    float2 c = ml[((size_t)16 + bnh) * S_ + s];
    float m = fmaxf(a.x, c.x);
    float w1 = a.y * __expf(a.x - m);
    float w2 = c.y * __expf(c.x - m);
    float inv = 1.f / (w1 + w2);
    w1 *= inv; w2 *= inv;
    short8 x1 = *(const short8*)(P1 + e);
    short8 x2 = *(const short8*)(P2 + e);
    short8 t;
#pragma unroll
    for (int i = 0; i < 8; i++)
        t[i] = f2bf(w1 * bf2f((unsigned short)x1[i]) + w2 * bf2f((unsigned short)x2[i]));
    *(short8*)(O + e) = t;
}

// ---------------------------------------------------------------------------
__global__ __launch_bounds__(256) void ln_kernel(
    const unsigned short* __restrict__ y, const float* __restrict__ g,
    const float* __restrict__ bta, unsigned short* __restrict__ out) {
    int row = blockIdx.x;
    size_t ro = (size_t)row * H_;
    int tid = threadIdx.x;
    float t[4]; float s = 0.f, s2 = 0.f;
#pragma unroll
    for (int i = 0; i < 4; i++) {
        int h = i * 256 + tid;
        float v = bf2f(y[ro + h]);
        t[i] = v; s += v; s2 += v * v;
    }
    s = wave64_sum(s); s2 = wave64_sum(s2);
    __shared__ float sh[8];
    int wave = tid >> 6, lane = tid & 63;
    if (lane == 0) { sh[wave] = s; sh[4 + wave] = s2; }
    __syncthreads();
    s  = sh[0] + sh[1] + sh[2] + sh[3];
    s2 = sh[4] + sh[5] + sh[6] + sh[7];
    float mu = s * (1.f / H_);
    float var = s2 * (1.f / H_) - mu * mu;
    float inv = rsqrtf(var + EPSF);
#pragma unroll
    for (int i = 0; i < 4; i++) {
        int h = i * 256 + tid;
        out[ro + h] = f2bf((t[i] - mu) * inv * g[h] + bta[h]);
    }
}

// ---------------------------------------------------------------------------
extern "C" void kernel_launch(void* const* d_in, const int* in_sizes, int n_in,
                              void* d_out, int out_size, void* d_ws, size_t ws_size,
                              hipStream_t stream) {
    const int*   ids          = (const int*)d_in[0];
    const float* embed        = (const float*)d_in[1];
    const float* nm_gate_w    = (const float*)d_in[2];
    const float* nm_gate_b    = (const float*)d_in[3];
    const float* nm_filter_w  = (const float*)d_in[4];
    const float* nm_filter_b  = (const float*)d_in[5];
    const float* nm_ctx_w     = (const float*)d_in[6];
    const float* nm_ctx_b     = (const float*)d_in[7];
    const float* q_w          = (const float*)d_in[8];
    const float* q_b          = (const float*)d_in[9];
    const float* k_w          = (const float*)d_in[10];
    const float* k_b          = (const float*)d_in[11];
    const float* v_w          = (const float*)d_in[12];
    const float* v_b          = (const float*)d_in[13];
    const float* gain_w       = (const float*)d_in[14];
    const float* gain_b       = (const float*)d_in[15];
    const float* attn_ow      = (const float*)d_in[16];
    const float* attn_ob      = (const float*)d_in[17];
    const float* en_w         = (const float*)d_in[18];
    const float* en_b         = (const float*)d_in[19];
    const float* plastic_w    = (const float*)d_in[20];
    const float* fix_w        = (const float*)d_in[21];
    const float* fix_b        = (const float*)d_in[22];
    const float* ln_g         = (const float*)d_in[23];
    const float* ln_b         = (const float*)d_in[24];
    const float* out_w        = (const float*)d_in[25];
    const float* out_b        = (const float*)d_in[26];

    size_t T  = (size_t)B_ * S_ * H_;
    size_t smallBytes = ((size_t)B_ * H_ + 2 * B_ + B_ * N_ + 8) * sizeof(float);
    size_t megaElems  = 26 * WH_ + WH_ / 4;
    size_t mlBytes    = (size_t)2 * 16 * S_ * sizeof(float2);
    size_t need_base  = 4 * T * 2 + smallBytes + 2 * WH_;
    size_t need_mega  = 4 * T * 2 + smallBytes + 2 * megaElems;
    size_t need_split = need_mega + 2 * T * 2 + mlBytes;
    if (ws_size < need_base) return;
    bool mega  = ws_size >= need_mega;
    bool split = ws_size >= need_split;

    unsigned short* X   = (unsigned short*)d_ws;
    unsigned short* Qb  = X + T;
    unsigned short* Kb  = Qb + T;
    unsigned short* Vb  = Kb + T;
    float* xmean  = (float*)(Vb + T);
    float* dopnor = xmean + (size_t)B_ * H_;
    float* qscale = dopnor + 2 * B_;
    unsigned short* Wbase = (unsigned short*)(qscale + B_ * N_ + 8);
    unsigned short* Pbuf  = Wbase + megaElems;      // 2T bf16 (split only)
    float2* mlbuf = (float2*)(Pbuf + 2 * T);        // (split only)
#define WOFF(k) (Wbase + (size_t)(k) * WH_)

    const int M   = B_ * S_;
    const int W8  = (int)(WH_ / 8);
    const int WG  = (W8 + 255) / 256;
    const int W84 = (int)(4 * WH_ / 8);
    const int WG4 = (W84 + 255) / 256;
    const int W8o = V_ * H_ / 8;
    const int WGo = (W8o + 255) / 256;

    if (mega) {
        wcvt_kernel<<<WG,  256, 0, stream>>>(nm_gate_w,   WOFF(0), W8);
        wcvt_kernel<<<WG,  256, 0, stream>>>(nm_filter_w, WOFF(1), W8);
        wcvt_qkv<<<WG4, 256, 0, stream>>>(q_w, WOFF(2), W84, 0);
        wcvt_qkv<<<WG4, 256, 0, stream>>>(k_w, WOFF(2), W84, 1);
        wcvt_qkv<<<WG4, 256, 0, stream>>>(v_w, WOFF(2), W84, 2);
        wcvt_kernel<<<WG4, 256, 0, stream>>>(attn_ow, WOFF(14), W84);
        wcvt_kernel<<<WG4, 256, 0, stream>>>(en_w,    WOFF(18), W84);
        wadd_kernel<<<WG4, 256, 0, stream>>>(fix_w, plastic_w, WOFF(22), W84);
        wcvt_kernel<<<WGo, 256, 0, stream>>>(out_w, WOFF(26), W8o);
    }

    gather_kernel<<<dim3((int)(T / 256)), 256, 0, stream>>>(ids, embed, X);

    hipMemsetAsync(xmean, 0, (size_t)B_ * H_ * sizeof(float), stream);
    mean_kernel<<<dim3(B_ * H_ / 256, 16), 256, 0, stream>>>(X, xmean);
    nm_kernel<<<1, 256, 0, stream>>>(xmean, nm_ctx_w, nm_ctx_b, dopnor);

    const unsigned short* Wp;
    if (mega) Wp = WOFF(0);
    else { wcvt_kernel<<<WG, 256, 0, stream>>>(nm_gate_w, Wbase, W8); Wp = Wbase; }
    gemm_bt<<<dim3(M / 128, H_ / 128), 256, 0, stream>>>(
        X, Wp, nm_gate_b, Qb, X, dopnor, H_, H_, 1);
    if (mega) Wp = WOFF(1);
    else { wcvt_kernel<<<WG, 256, 0, stream>>>(nm_filter_w, Wbase, W8); Wp = Wbase; }
    gemm_bt<<<dim3(M / 128, H_ / 128), 256, 0, stream>>>(
        Qb, Wp, nm_filter_b, X, Qb, dopnor, H_, H_, 2);

    for (int l = 0; l < L_; l++) {
        size_t wo = (size_t)l * WH_;
        size_t bo = (size_t)l * H_;
        hipMemsetAsync(xmean, 0, (size_t)B_ * H_ * sizeof(float), stream);
        mean_kernel<<<dim3(B_ * H_ / 256, 16), 256, 0, stream>>>(X, xmean);
        gain_kernel<<<1, 256, 0, stream>>>(xmean, gain_w + (size_t)l * N_ * H_,
                                           gain_b + (size_t)l * N_, qscale);

        if (mega) {
            gemm_qkv<<<dim3(M / 128, 3 * H_ / 128), 256, 0, stream>>>(
                X, WOFF(2) + (size_t)l * 3 * WH_, q_b + bo, k_b + bo, v_b + bo,
                Qb, Kb, Vb);
        } else {
            wcvt_kernel<<<WG, 256, 0, stream>>>(q_w + wo, Wbase, W8);
            gemm_bt<<<dim3(M / 128, H_ / 128), 256, 0, stream>>>(
                X, Wbase, q_b + bo, Qb, nullptr, nullptr, H_, H_, 0);
            wcvt_kernel<<<WG, 256, 0, stream>>>(k_w + wo, Wbase, W8);
            gemm_bt<<<dim3(M / 128, H_ / 128), 256, 0, stream>>>(
                X, Wbase, k_b + bo, Kb, nullptr, nullptr, H_, H_, 0);
            wcvt_kernel<<<WG, 256, 0, stream>>>(v_w + wo, Wbase, W8);
            gemm_bt<<<dim3(M / 128, H_ / 128), 256, 0, stream>>>(
                X, Wbase, v_b + bo, Vb, nullptr, nullptr, H_, H_, 6);
        }

        if (split) {
            flash_split<<<dim3(S_ / 256, 2, B_ * N_), 512, 0, stream>>>(
                Qb, Kb, Vb, qscale, Pbuf, mlbuf);
            flash_merge<<<dim3((int)(T / 8 / 256)), 256, 0, stream>>>(
                Pbuf, Pbuf + T, mlbuf, Qb);
        } else {
            flash_attn<<<dim3(S_ / 128, B_ * N_), 512, 0, stream>>>(
                Qb, Kb, Vb, qscale, Qb);
        }

        if (mega) Wp = WOFF(14) + wo;
        else { wcvt_kernel<<<WG, 256, 0, stream>>>(attn_ow + wo, Wbase, W8); Wp = Wbase; }
        gemm_bt<<<dim3(M / 128, H_ / 128), 256, 0, stream>>>(
            Qb, Wp, attn_ob + bo, Kb, X, nullptr, H_, H_, 3);
        if (mega) Wp = WOFF(18) + wo;
        else { wcvt_kernel<<<WG, 256, 0, stream>>>(en_w + wo, Wbase, W8); Wp = Wbase; }
        gemm_bt<<<dim3(M / 128, H_ / 128), 256, 0, stream>>>(
            Kb, Wp, en_b + bo, Vb, nullptr, nullptr, H_, H_, 4);
        if (mega) Wp = WOFF(22) + wo;
        else { wadd_kernel<<<WG, 256, 0, stream>>>(fix_w + wo, plastic_w + wo, Wbase, W8); Wp = Wbase; }
        gemm_bt<<<dim3(M / 128, H_ / 128), 256, 0, stream>>>(
            Vb, Wp, fix_b + bo, Qb, nullptr, nullptr, H_, H_, 0);
        ln_kernel<<<dim3(M), 256, 0, stream>>>(Qb, ln_g + bo, ln_b + bo, X);
    }

    if (mega) Wp = WOFF(26);
    else { wcvt_kernel<<<WGo, 256, 0, stream>>>(out_w, Wbase, W8o); Wp = Wbase; }
    gemm_bt<<<dim3(M / 128, V_ / 128), 256, 0, stream>>>(
        X, Wp, out_b, (float*)d_out, nullptr, nullptr, H_, V_, 5);
#undef WOFF
}

// Round 7
// 1923.868 us; speedup vs baseline: 1.1806x; 1.1806x over previous
//
#include <hip/hip_runtime.h>

#define B_ 4
#define S_ 2048
#define H_ 1024
#define L_ 4
#define N_ 4
#define D_ 256
#define V_ 256
#define EPSF 1e-5f
#define WH_ ((size_t)H_ * H_)   // 1<<20

typedef __attribute__((ext_vector_type(8))) short short8;
typedef __attribute__((ext_vector_type(4))) float f32x4;

__device__ inline float bf2f(unsigned short u) {
    union { unsigned int ui; float f; } c; c.ui = ((unsigned int)u) << 16; return c.f;
}
__device__ inline unsigned short f2bf(float f) {
    union { float f; unsigned int ui; } c; c.f = f;
    unsigned int u = c.ui;
    unsigned int r = (u + 0x7FFFu + ((u >> 16) & 1u)) >> 16;
    return (unsigned short)r;
}
__device__ inline float wave64_sum(float v) {
    for (int m = 32; m >= 1; m >>= 1) v += __shfl_xor(v, m, 64);
    return v;
}
__device__ inline void gl_lds16(const unsigned short* g, unsigned short* l) {
    __builtin_amdgcn_global_load_lds(
        (const __attribute__((address_space(1))) unsigned int*)g,
        (__attribute__((address_space(3))) unsigned int*)l, 16, 0, 0);
}

// ---------------------------------------------------------------------------
__global__ void wcvt_kernel(const float* __restrict__ W,
                            unsigned short* __restrict__ Wb, int n8) {
    int idx = blockIdx.x * 256 + threadIdx.x;
    if (idx >= n8) return;
    size_t base = (size_t)idx * 8;
    float4 a0 = *(const float4*)(W + base);
    float4 a1 = *(const float4*)(W + base + 4);
    short8 t;
    t[0] = f2bf(a0.x); t[1] = f2bf(a0.y); t[2] = f2bf(a0.z); t[3] = f2bf(a0.w);
    t[4] = f2bf(a1.x); t[5] = f2bf(a1.y); t[6] = f2bf(a1.z); t[7] = f2bf(a1.w);
    *(short8*)(Wb + base) = t;
}

// fp32 -> bf16 into QKV-fused layout: src (L,WH) -> dst layer*3WH + sel*WH
__global__ void wcvt_qkv(const float* __restrict__ W,
                         unsigned short* __restrict__ Wb, int n8, int sel) {
    int idx = blockIdx.x * 256 + threadIdx.x;
    if (idx >= n8) return;
    size_t p = (size_t)idx * 8;
    size_t layer = p >> 20;
    size_t within = p & (WH_ - 1);
    size_t dst = layer * 3 * WH_ + (size_t)sel * WH_ + within;
    float4 a0 = *(const float4*)(W + p);
    float4 a1 = *(const float4*)(W + p + 4);
    short8 t;
    t[0] = f2bf(a0.x); t[1] = f2bf(a0.y); t[2] = f2bf(a0.z); t[3] = f2bf(a0.w);
    t[4] = f2bf(a1.x); t[5] = f2bf(a1.y); t[6] = f2bf(a1.z); t[7] = f2bf(a1.w);
    *(short8*)(Wb + dst) = t;
}

// combined weight: Wo = bf16(Wa + Wb2 + I) per HxH layer (layers contiguous)
__global__ void wadd_kernel(const float* __restrict__ Wa, const float* __restrict__ Wb2,
                            unsigned short* __restrict__ Wo, int n8) {
    int idx = blockIdx.x * 256 + threadIdx.x;
    if (idx >= n8) return;
    size_t base = (size_t)idx * 8;
    short8 t;
#pragma unroll
    for (int e = 0; e < 8; e++) {
        size_t p = base + e;
        int pos = (int)(p & (WH_ - 1));
        float v = Wa[p] + Wb2[p] + (((pos >> 10) == (pos & (H_ - 1))) ? 1.f : 0.f);
        t[e] = f2bf(v);
    }
    *(short8*)(Wo + base) = t;
}

// ---------------------------------------------------------------------------
__global__ void gather_kernel(const int* __restrict__ ids,
                              const float* __restrict__ embed,
                              unsigned short* __restrict__ x) {
    size_t idx = (size_t)blockIdx.x * 256 + threadIdx.x;
    int bs = (int)(idx >> 10);
    int h  = (int)(idx & 1023);
    x[idx] = f2bf(embed[(size_t)ids[bs] * H_ + h]);
}

__global__ void mean_kernel(const unsigned short* __restrict__ Xin,
                            float* __restrict__ xmean) {
    int idx = blockIdx.x * 256 + threadIdx.x;
    int b = idx >> 10, h = idx & 1023;
    int s0 = blockIdx.y * 128;
    const unsigned short* p = Xin + ((size_t)b * S_ + s0) * H_ + h;
    float s = 0.f;
    for (int i = 0; i < 128; i++) s += bf2f(p[(size_t)i * H_]);
    atomicAdd(&xmean[idx], s);
}

__global__ void nm_kernel(const float* __restrict__ xmean,
                          const float* __restrict__ w,
                          const float* __restrict__ bias,
                          float* __restrict__ dopnor) {
    int wave = threadIdx.x >> 6, lane = threadIdx.x & 63;
    for (int p = wave; p < 2 * B_; p += 4) {
        int b = p >> 1, j = p & 1;
        float s = 0.f;
        for (int h = lane; h < H_; h += 64) s += xmean[b * H_ + h] * w[j * H_ + h];
        s = wave64_sum(s);
        if (lane == 0) dopnor[p] = s / (float)S_ + bias[j];
    }
}

__global__ void gain_kernel(const float* __restrict__ xmean,
                            const float* __restrict__ gw,
                            const float* __restrict__ gb,
                            float* __restrict__ qscale) {
    int wave = threadIdx.x >> 6, lane = threadIdx.x & 63;
    for (int p = wave; p < B_ * N_; p += 4) {
        int b = p >> 2, n = p & 3;
        float s = 0.f;
        for (int h = lane; h < H_; h += 64) s += xmean[b * H_ + h] * gw[n * H_ + h];
        s = wave64_sum(s);
        if (lane == 0) qscale[p] = (1.f + s / (float)S_ + gb[n]) * 0.0625f;
    }
}

// ---------------------------------------------------------------------------
// GEMM (m97 structure): C(MxN) = epilogue( A(MxK) @ W(NxK)^T + bias )
// modes: 0 plain->bf16; 1 gate; 2 noise; 3 residual; 4 silu; 5 plain->fp32;
//        6 V^T store
// ---------------------------------------------------------------------------
__global__ __launch_bounds__(256) void gemm_bt(
    const unsigned short* __restrict__ A, const unsigned short* __restrict__ W,
    const float* __restrict__ bias, void* __restrict__ Cout,
    const unsigned short* __restrict__ X, const float* __restrict__ scal,
    int K, int Nout, int mode) {
    __shared__ unsigned short As[128 * 32];
    __shared__ unsigned short Bs[128 * 32];
    int tid = threadIdx.x;
    int wave = tid >> 6, lane = tid & 63;
    int quad = lane >> 4, l16 = lane & 15;
    int bm = blockIdx.x * 128;
    int bn = blockIdx.y * 128;
    int mw = (wave >> 1) * 64, nw = (wave & 1) * 64;

    const unsigned short* Ag = A + (size_t)(bm + wave * 16 + (lane >> 2)) * K + (lane & 3) * 8;
    const unsigned short* Wg = W + (size_t)(bn + wave * 16 + (lane >> 2)) * K + (lane & 3) * 8;
    unsigned short* ldsA = As + wave * 512;
    unsigned short* ldsB = Bs + wave * 512;
    size_t rowskip = (size_t)64 * K;

    f32x4 acc[4][4];
#pragma unroll
    for (int i = 0; i < 4; i++)
#pragma unroll
        for (int j = 0; j < 4; j++)
#pragma unroll
            for (int r = 0; r < 4; r++) acc[i][j][r] = 0.f;

    for (int kk = 0; kk < K; kk += 32) {
        __syncthreads();
        gl_lds16(Ag + kk, ldsA);
        gl_lds16(Ag + rowskip + kk, ldsA + 2048);
        gl_lds16(Wg + kk, ldsB);
        gl_lds16(Wg + rowskip + kk, ldsB + 2048);
        __syncthreads();

        short8 af[4], bfr[4];
#pragma unroll
        for (int i = 0; i < 4; i++)
            af[i] = *(const short8*)&As[(mw + i * 16 + l16) * 32 + quad * 8];
#pragma unroll
        for (int j = 0; j < 4; j++)
            bfr[j] = *(const short8*)&Bs[(nw + j * 16 + l16) * 32 + quad * 8];
#pragma unroll
        for (int i = 0; i < 4; i++)
#pragma unroll
            for (int j = 0; j < 4; j++)
                acc[i][j] = __builtin_amdgcn_mfma_f32_16x16x32_bf16(af[i], bfr[j], acc[i][j], 0, 0, 0);
    }

    if (mode == 6) {
#pragma unroll
        for (int i = 0; i < 4; i++) {
#pragma unroll
            for (int j = 0; j < 4; j++) {
                int col = bn + nw + j * 16 + l16;
                float bv = bias ? bias[col] : 0.f;
                int n = col >> 8, d = col & 255;
                int row0 = bm + mw + i * 16 + quad * 4;
                int b = row0 >> 11, s0 = row0 & 2047;
                union { unsigned short u[4]; uint2 v; } pk;
#pragma unroll
                for (int r = 0; r < 4; r++) pk.u[r] = f2bf(acc[i][j][r] + bv);
                *(uint2*)((unsigned short*)Cout +
                          ((size_t)(b * N_ + n) * D_ + d) * S_ + s0) = pk.v;
            }
        }
        return;
    }

#pragma unroll
    for (int i = 0; i < 4; i++) {
#pragma unroll
        for (int j = 0; j < 4; j++) {
            int col = bn + nw + j * 16 + l16;
            float bv = bias ? bias[col] : 0.f;
#pragma unroll
            for (int r = 0; r < 4; r++) {
                int row = bm + mw + i * 16 + quad * 4 + r;
                float v = acc[i][j][r] + bv;
                size_t off = (size_t)row * Nout + col;
                if (mode == 5) {
                    ((float*)Cout)[off] = v;
                    continue;
                }
                float outv;
                if (mode == 0) {
                    outv = v;
                } else if (mode == 1) {
                    float sig = 1.f / (1.f + __expf(-v));
                    float dop = scal[(row >> 11) * 2];
                    outv = bf2f(X[off]) * (1.f + dop * sig);
                } else if (mode == 2) {
                    float nor = scal[(row >> 11) * 2 + 1];
                    outv = bf2f(X[off]) + nor * tanhf(v);
                } else if (mode == 3) {
                    outv = v + bf2f(X[off]);
                } else {
                    outv = v * (1.f / (1.f + __expf(-v)));
                }
                ((unsigned short*)Cout)[off] = f2bf(outv);
            }
        }
    }
}

// ---------------------------------------------------------------------------
// Fused QKV GEMM: W is (3H x H) fused [q;k;v] for one layer. N=3072.
// col block (64-aligned) selects destination: 0 -> Q, 1 -> K, 2 -> V^T store.
// ---------------------------------------------------------------------------
__global__ __launch_bounds__(256) void gemm_qkv(
    const unsigned short* __restrict__ A, const unsigned short* __restrict__ W,
    const float* __restrict__ qb, const float* __restrict__ kb,
    const float* __restrict__ vbb, unsigned short* __restrict__ Qo,
    unsigned short* __restrict__ Ko, unsigned short* __restrict__ Vt) {
    __shared__ unsigned short As[128 * 32];
    __shared__ unsigned short Bs[128 * 32];
    const int K = H_;
    int tid = threadIdx.x;
    int wave = tid >> 6, lane = tid & 63;
    int quad = lane >> 4, l16 = lane & 15;
    int bm = blockIdx.x * 128;
    int bn = blockIdx.y * 128;
    int mw = (wave >> 1) * 64, nw = (wave & 1) * 64;

    const unsigned short* Ag = A + (size_t)(bm + wave * 16 + (lane >> 2)) * K + (lane & 3) * 8;
    const unsigned short* Wg = W + (size_t)(bn + wave * 16 + (lane >> 2)) * K + (lane & 3) * 8;
    unsigned short* ldsA = As + wave * 512;
    unsigned short* ldsB = Bs + wave * 512;
    size_t rowskip = (size_t)64 * K;

    f32x4 acc[4][4];
#pragma unroll
    for (int i = 0; i < 4; i++)
#pragma unroll
        for (int j = 0; j < 4; j++)
#pragma unroll
            for (int r = 0; r < 4; r++) acc[i][j][r] = 0.f;

    for (int kk = 0; kk < K; kk += 32) {
        __syncthreads();
        gl_lds16(Ag + kk, ldsA);
        gl_lds16(Ag + rowskip + kk, ldsA + 2048);
        gl_lds16(Wg + kk, ldsB);
        gl_lds16(Wg + rowskip + kk, ldsB + 2048);
        __syncthreads();

        short8 af[4], bfr[4];
#pragma unroll
        for (int i = 0; i < 4; i++)
            af[i] = *(const short8*)&As[(mw + i * 16 + l16) * 32 + quad * 8];
#pragma unroll
        for (int j = 0; j < 4; j++)
            bfr[j] = *(const short8*)&Bs[(nw + j * 16 + l16) * 32 + quad * 8];
#pragma unroll
        for (int i = 0; i < 4; i++)
#pragma unroll
            for (int j = 0; j < 4; j++)
                acc[i][j] = __builtin_amdgcn_mfma_f32_16x16x32_bf16(af[i], bfr[j], acc[i][j], 0, 0, 0);
    }

    int sel = (bn + nw) >> 10;   // uniform per block-half
    if (sel == 2) {
#pragma unroll
        for (int i = 0; i < 4; i++) {
#pragma unroll
            for (int j = 0; j < 4; j++) {
                int c2 = ((bn + nw) & 1023) + j * 16 + l16;
                float bv = vbb[c2];
                int n = c2 >> 8, d = c2 & 255;
                int row0 = bm + mw + i * 16 + quad * 4;
                int b = row0 >> 11, s0 = row0 & 2047;
                union { unsigned short u[4]; uint2 v; } pk;
#pragma unroll
                for (int r = 0; r < 4; r++) pk.u[r] = f2bf(acc[i][j][r] + bv);
                *(uint2*)(Vt + ((size_t)(b * N_ + n) * D_ + d) * S_ + s0) = pk.v;
            }
        }
    } else {
        unsigned short* Co = (sel == 0) ? Qo : Ko;
        const float* bias = (sel == 0) ? qb : kb;
#pragma unroll
        for (int i = 0; i < 4; i++) {
#pragma unroll
            for (int j = 0; j < 4; j++) {
                int c2 = ((bn + nw) & 1023) + j * 16 + l16;
                float bv = bias[c2];
#pragma unroll
                for (int r = 0; r < 4; r++) {
                    int row = bm + mw + i * 16 + quad * 4 + r;
                    Co[(size_t)row * H_ + c2] = f2bf(acc[i][j][r] + bv);
                }
            }
        }
    }
}

// ---------------------------------------------------------------------------
// Flash attention: 256 thr = 4 waves x 32 q-rows (2 row-tiles), full t-range.
// Grid (S/128, B*N) = 256 blocks. K staged [64][264]; V^T staged [272][72]
// (rows 256+ = ones-tile: row-sum accumulates in MFMA). kf/vf LDS reads
// amortized across the 2 row-tiles. Out in-place to O (== Q buffer).
// ---------------------------------------------------------------------------
__global__ __launch_bounds__(256) void flash_attn(
    const unsigned short* __restrict__ Q, const unsigned short* __restrict__ Kg,
    const unsigned short* __restrict__ VT, const float* __restrict__ qscale,
    unsigned short* __restrict__ O) {
    __shared__ unsigned short Kt[64][264];
    __shared__ unsigned short Vtl[272][72];
    __shared__ unsigned short Pl[4][32][72];

    int tid = threadIdx.x;
    int wave = tid >> 6, lane = tid & 63;
    int quad = lane >> 4, l16 = lane & 15;
    int bnh = blockIdx.y;
    size_t base = ((size_t)(bnh >> 2) * S_) * H_ + (size_t)(bnh & 3) * D_;
    size_t vtbase = (size_t)bnh * D_ * S_;
    int qw = blockIdx.x * 128 + wave * 32;
    float scale = qscale[bnh];

    for (int c = tid; c < 16 * 72; c += 256) {
        int rr = c / 72, cc = c - rr * 72;
        Vtl[256 + rr][cc] = (rr == 0) ? (unsigned short)0x3F80 : (unsigned short)0;
    }

    short8 qf[2][8];
#pragma unroll
    for (int rt = 0; rt < 2; rt++)
#pragma unroll
        for (int kk = 0; kk < 8; kk++)
            qf[rt][kk] = *(const short8*)(Q + base +
                (size_t)(qw + rt * 16 + l16) * H_ + kk * 32 + quad * 8);

    f32x4 o[2][16], osum[2];
#pragma unroll
    for (int rt = 0; rt < 2; rt++) {
#pragma unroll
        for (int c = 0; c < 16; c++)
#pragma unroll
            for (int r = 0; r < 4; r++) o[rt][c][r] = 0.f;
#pragma unroll
        for (int r = 0; r < 4; r++) osum[rt][r] = 0.f;
    }
    float mrow[2][4];
#pragma unroll
    for (int rt = 0; rt < 2; rt++)
#pragma unroll
        for (int r = 0; r < 4; r++) mrow[rt][r] = -1e30f;

    for (int t0 = 0; t0 < S_; t0 += 64) {
        __syncthreads();
        // stage K tile 64x256: 8 chunks of 16B per thread
#pragma unroll
        for (int rr = 0; rr < 8; rr++) {
            int c = rr * 256 + tid;
            int row = c >> 5, col = (c & 31) * 8;
            *(short8*)&Kt[row][col] =
                *(const short8*)(Kg + base + (size_t)(t0 + row) * H_ + col);
        }
        // stage V^T tile 256x64
#pragma unroll
        for (int rr = 0; rr < 8; rr++) {
            int c = rr * 256 + tid;
            int d = c >> 3, col = (c & 7) * 8;
            *(short8*)&Vtl[d][col] =
                *(const short8*)(VT + vtbase + (size_t)d * S_ + t0 + col);
        }
        __syncthreads();

        // QK^T for both row-tiles, kf read once
        f32x4 s0[4], s1[4];
#pragma unroll
        for (int j = 0; j < 4; j++)
#pragma unroll
            for (int r = 0; r < 4; r++) { s0[j][r] = 0.f; s1[j][r] = 0.f; }
#pragma unroll
        for (int j = 0; j < 4; j++)
#pragma unroll
            for (int kk = 0; kk < 8; kk++) {
                short8 kf = *(const short8*)&Kt[j * 16 + l16][kk * 32 + quad * 8];
                s0[j] = __builtin_amdgcn_mfma_f32_16x16x32_bf16(qf[0][kk], kf, s0[j], 0, 0, 0);
                s1[j] = __builtin_amdgcn_mfma_f32_16x16x32_bf16(qf[1][kk], kf, s1[j], 0, 0, 0);
            }

        // online softmax per row-tile
#pragma unroll
        for (int rt = 0; rt < 2; rt++) {
            float alpha[4];
#pragma unroll
            for (int r = 0; r < 4; r++) {
                float sv[4];
#pragma unroll
                for (int j = 0; j < 4; j++)
                    sv[j] = (rt == 0 ? s0[j][r] : s1[j][r]) * scale;
                float mx = fmaxf(fmaxf(sv[0], sv[1]), fmaxf(sv[2], sv[3]));
                for (int m = 8; m >= 1; m >>= 1) mx = fmaxf(mx, __shfl_xor(mx, m, 64));
                float mnew = fmaxf(mrow[rt][r], mx);
                alpha[r] = __expf(mrow[rt][r] - mnew);
                mrow[rt][r] = mnew;
#pragma unroll
                for (int j = 0; j < 4; j++)
                    Pl[wave][rt * 16 + quad * 4 + r][j * 16 + l16] =
                        f2bf(__expf(sv[j] - mnew));
            }
#pragma unroll
            for (int c = 0; c < 16; c++)
#pragma unroll
                for (int r = 0; r < 4; r++) o[rt][c][r] *= alpha[r];
#pragma unroll
            for (int r = 0; r < 4; r++) osum[rt][r] *= alpha[r];
        }

        // PV for both row-tiles, vf read once
        short8 pf[2][2];
#pragma unroll
        for (int rt = 0; rt < 2; rt++) {
            pf[rt][0] = *(const short8*)&Pl[wave][rt * 16 + l16][quad * 8];
            pf[rt][1] = *(const short8*)&Pl[wave][rt * 16 + l16][32 + quad * 8];
        }
#pragma unroll
        for (int c = 0; c < 16; c++) {
            short8 vf0 = *(const short8*)&Vtl[c * 16 + l16][quad * 8];
            o[0][c] = __builtin_amdgcn_mfma_f32_16x16x32_bf16(pf[0][0], vf0, o[0][c], 0, 0, 0);
            o[1][c] = __builtin_amdgcn_mfma_f32_16x16x32_bf16(pf[1][0], vf0, o[1][c], 0, 0, 0);
            short8 vf1 = *(const short8*)&Vtl[c * 16 + l16][32 + quad * 8];
            o[0][c] = __builtin_amdgcn_mfma_f32_16x16x32_bf16(pf[0][1], vf1, o[0][c], 0, 0, 0);
            o[1][c] = __builtin_amdgcn_mfma_f32_16x16x32_bf16(pf[1][1], vf1, o[1][c], 0, 0, 0);
        }
        {
            short8 vs0 = *(const short8*)&Vtl[256 + l16][quad * 8];
            short8 vs1 = *(const short8*)&Vtl[256 + l16][32 + quad * 8];
            osum[0] = __builtin_amdgcn_mfma_f32_16x16x32_bf16(pf[0][0], vs0, osum[0], 0, 0, 0);
            osum[0] = __builtin_amdgcn_mfma_f32_16x16x32_bf16(pf[0][1], vs1, osum[0], 0, 0, 0);
            osum[1] = __builtin_amdgcn_mfma_f32_16x16x32_bf16(pf[1][0], vs0, osum[1], 0, 0, 0);
            osum[1] = __builtin_amdgcn_mfma_f32_16x16x32_bf16(pf[1][1], vs1, osum[1], 0, 0, 0);
        }
    }

#pragma unroll
    for (int rt = 0; rt < 2; rt++) {
        float invl[4];
#pragma unroll
        for (int r = 0; r < 4; r++)
            invl[r] = 1.f / __shfl(osum[rt][r], (lane & 48), 64);
#pragma unroll
        for (int c = 0; c < 16; c++)
#pragma unroll
            for (int r = 0; r < 4; r++) {
                int row = qw + rt * 16 + quad * 4 + r;
                int d = c * 16 + l16;
                O[base + (size_t)row * H_ + d] = f2bf(o[rt][c][r] * invl[r]);
            }
    }
}

// ---------------------------------------------------------------------------
__global__ __launch_bounds__(256) void ln_kernel(
    const unsigned short* __restrict__ y, const float* __restrict__ g,
    const float* __restrict__ bta, unsigned short* __restrict__ out) {
    int row = blockIdx.x;
    size_t ro = (size_t)row * H_;
    int tid = threadIdx.x;
    float t[4]; float s = 0.f, s2 = 0.f;
#pragma unroll
    for (int i = 0; i < 4; i++) {
        int h = i * 256 + tid;
        float v = bf2f(y[ro + h]);
        t[i] = v; s += v; s2 += v * v;
    }
    s = wave64_sum(s); s2 = wave64_sum(s2);
    __shared__ float sh[8];
    int wave = tid >> 6, lane = tid & 63;
    if (lane == 0) { sh[wave] = s; sh[4 + wave] = s2; }
    __syncthreads();
    s  = sh[0] + sh[1] + sh[2] + sh[3];
    s2 = sh[4] + sh[5] + sh[6] + sh[7];
    float mu = s * (1.f / H_);
    float var = s2 * (1.f / H_) - mu * mu;
    float inv = rsqrtf(var + EPSF);
#pragma unroll
    for (int i = 0; i < 4; i++) {
        int h = i * 256 + tid;
        out[ro + h] = f2bf((t[i] - mu) * inv * g[h] + bta[h]);
    }
}

// ---------------------------------------------------------------------------
extern "C" void kernel_launch(void* const* d_in, const int* in_sizes, int n_in,
                              void* d_out, int out_size, void* d_ws, size_t ws_size,
                              hipStream_t stream) {
    const int*   ids          = (const int*)d_in[0];
    const float* embed        = (const float*)d_in[1];
    const float* nm_gate_w    = (const float*)d_in[2];
    const float* nm_gate_b    = (const float*)d_in[3];
    const float* nm_filter_w  = (const float*)d_in[4];
    const float* nm_filter_b  = (const float*)d_in[5];
    const float* nm_ctx_w     = (const float*)d_in[6];
    const float* nm_ctx_b     = (const float*)d_in[7];
    const float* q_w          = (const float*)d_in[8];
    const float* q_b          = (const float*)d_in[9];
    const float* k_w          = (const float*)d_in[10];
    const float* k_b          = (const float*)d_in[11];
    const float* v_w          = (const float*)d_in[12];
    const float* v_b          = (const float*)d_in[13];
    const float* gain_w       = (const float*)d_in[14];
    const float* gain_b       = (const float*)d_in[15];
    const float* attn_ow      = (const float*)d_in[16];
    const float* attn_ob      = (const float*)d_in[17];
    const float* en_w         = (const float*)d_in[18];
    const float* en_b         = (const float*)d_in[19];
    const float* plastic_w    = (const float*)d_in[20];
    const float* fix_w        = (const float*)d_in[21];
    const float* fix_b        = (const float*)d_in[22];
    const float* ln_g         = (const float*)d_in[23];
    const float* ln_b         = (const float*)d_in[24];
    const float* out_w        = (const float*)d_in[25];
    const float* out_b        = (const float*)d_in[26];

    size_t T  = (size_t)B_ * S_ * H_;
    size_t smallBytes = ((size_t)B_ * H_ + 2 * B_ + B_ * N_ + 8) * sizeof(float);
    size_t megaElems  = 26 * WH_ + WH_ / 4;
    size_t need_base  = 4 * T * 2 + smallBytes + 2 * WH_;
    size_t need_mega  = 4 * T * 2 + smallBytes + 2 * megaElems;
    if (ws_size < need_base) return;
    bool mega = ws_size >= need_mega;

    unsigned short* X   = (unsigned short*)d_ws;
    unsigned short* Qb  = X + T;
    unsigned short* Kb  = Qb + T;
    unsigned short* Vb  = Kb + T;
    float* xmean  = (float*)(Vb + T);
    float* dopnor = xmean + (size_t)B_ * H_;
    float* qscale = dopnor + 2 * B_;
    unsigned short* Wbase = (unsigned short*)(qscale + B_ * N_ + 8);
#define WOFF(k) (Wbase + (size_t)(k) * WH_)

    const int M   = B_ * S_;
    const int W8  = (int)(WH_ / 8);
    const int WG  = (W8 + 255) / 256;
    const int W84 = (int)(4 * WH_ / 8);
    const int WG4 = (W84 + 255) / 256;
    const int W8o = V_ * H_ / 8;
    const int WGo = (W8o + 255) / 256;

    if (mega) {
        wcvt_kernel<<<WG,  256, 0, stream>>>(nm_gate_w,   WOFF(0), W8);
        wcvt_kernel<<<WG,  256, 0, stream>>>(nm_filter_w, WOFF(1), W8);
        wcvt_qkv<<<WG4, 256, 0, stream>>>(q_w, WOFF(2), W84, 0);
        wcvt_qkv<<<WG4, 256, 0, stream>>>(k_w, WOFF(2), W84, 1);
        wcvt_qkv<<<WG4, 256, 0, stream>>>(v_w, WOFF(2), W84, 2);
        wcvt_kernel<<<WG4, 256, 0, stream>>>(attn_ow, WOFF(14), W84);
        wcvt_kernel<<<WG4, 256, 0, stream>>>(en_w,    WOFF(18), W84);
        wadd_kernel<<<WG4, 256, 0, stream>>>(fix_w, plastic_w, WOFF(22), W84);
        wcvt_kernel<<<WGo, 256, 0, stream>>>(out_w, WOFF(26), W8o);
    }

    gather_kernel<<<dim3((int)(T / 256)), 256, 0, stream>>>(ids, embed, X);

    hipMemsetAsync(xmean, 0, (size_t)B_ * H_ * sizeof(float), stream);
    mean_kernel<<<dim3(B_ * H_ / 256, 16), 256, 0, stream>>>(X, xmean);
    nm_kernel<<<1, 256, 0, stream>>>(xmean, nm_ctx_w, nm_ctx_b, dopnor);

    const unsigned short* Wp;
    if (mega) Wp = WOFF(0);
    else { wcvt_kernel<<<WG, 256, 0, stream>>>(nm_gate_w, Wbase, W8); Wp = Wbase; }
    gemm_bt<<<dim3(M / 128, H_ / 128), 256, 0, stream>>>(
        X, Wp, nm_gate_b, Qb, X, dopnor, H_, H_, 1);
    if (mega) Wp = WOFF(1);
    else { wcvt_kernel<<<WG, 256, 0, stream>>>(nm_filter_w, Wbase, W8); Wp = Wbase; }
    gemm_bt<<<dim3(M / 128, H_ / 128), 256, 0, stream>>>(
        Qb, Wp, nm_filter_b, X, Qb, dopnor, H_, H_, 2);

    for (int l = 0; l < L_; l++) {
        size_t wo = (size_t)l * WH_;
        size_t bo = (size_t)l * H_;
        hipMemsetAsync(xmean, 0, (size_t)B_ * H_ * sizeof(float), stream);
        mean_kernel<<<dim3(B_ * H_ / 256, 16), 256, 0, stream>>>(X, xmean);
        gain_kernel<<<1, 256, 0, stream>>>(xmean, gain_w + (size_t)l * N_ * H_,
                                           gain_b + (size_t)l * N_, qscale);

        if (mega) {
            gemm_qkv<<<dim3(M / 128, 3 * H_ / 128), 256, 0, stream>>>(
                X, WOFF(2) + (size_t)l * 3 * WH_, q_b + bo, k_b + bo, v_b + bo,
                Qb, Kb, Vb);
        } else {
            wcvt_kernel<<<WG, 256, 0, stream>>>(q_w + wo, Wbase, W8);
            gemm_bt<<<dim3(M / 128, H_ / 128), 256, 0, stream>>>(
                X, Wbase, q_b + bo, Qb, nullptr, nullptr, H_, H_, 0);
            wcvt_kernel<<<WG, 256, 0, stream>>>(k_w + wo, Wbase, W8);
            gemm_bt<<<dim3(M / 128, H_ / 128), 256, 0, stream>>>(
                X, Wbase, k_b + bo, Kb, nullptr, nullptr, H_, H_, 0);
            wcvt_kernel<<<WG, 256, 0, stream>>>(v_w + wo, Wbase, W8);
            gemm_bt<<<dim3(M / 128, H_ / 128), 256, 0, stream>>>(
                X, Wbase, v_b + bo, Vb, nullptr, nullptr, H_, H_, 6);
        }

        flash_attn<<<dim3(S_ / 128, B_ * N_), 256, 0, stream>>>(
            Qb, Kb, Vb, qscale, Qb);

        if (mega) Wp = WOFF(14) + wo;
        else { wcvt_kernel<<<WG, 256, 0, stream>>>(attn_ow + wo, Wbase, W8); Wp = Wbase; }
        gemm_bt<<<dim3(M / 128, H_ / 128), 256, 0, stream>>>(
            Qb, Wp, attn_ob + bo, Kb, X, nullptr, H_, H_, 3);
        if (mega) Wp = WOFF(18) + wo;
        else { wcvt_kernel<<<WG, 256, 0, stream>>>(en_w + wo, Wbase, W8); Wp = Wbase; }
        gemm_bt<<<dim3(M / 128, H_ / 128), 256, 0, stream>>>(
            Kb, Wp, en_b + bo, Vb, nullptr, nullptr, H_, H_, 4);
        if (mega) Wp = WOFF(22) + wo;
        else { wadd_kernel<<<WG, 256, 0, stream>>>(fix_w + wo, plastic_w + wo, Wbase, W8); Wp = Wbase; }
        gemm_bt<<<dim3(M / 128, H_ / 128), 256, 0, stream>>>(
            Vb, Wp, fix_b + bo, Qb, nullptr, nullptr, H_, H_, 0);
        ln_kernel<<<dim3(M), 256, 0, stream>>>(Qb, ln_g + bo, ln_b + bo, X);
    }

    if (mega) Wp = WOFF(26);
    else { wcvt_kernel<<<WGo, 256, 0, stream>>>(out_w, Wbase, W8o); Wp = Wbase; }
    gemm_bt<<<dim3(M / 128, V_ / 128), 256, 0, stream>>>(
        X, Wp, out_b, (float*)d_out, nullptr, nullptr, H_, V_, 5);
#undef WOFF
}